// Round 21
// baseline (79.205 us; speedup 1.0000x reference)
//
#include <hip/hip_runtime.h>
#include <hip/hip_bf16.h>
#include <math.h>
#include <stdint.h>

#define B 4
#define CLOW 512
#define CHIGH 256
#define KC 64
#define VC 64
#define N 4096  // 64*64 tokens

typedef __attribute__((ext_vector_type(8))) short bf16x8;
typedef __attribute__((ext_vector_type(4))) short bf16x4;
typedef __attribute__((ext_vector_type(4))) float f32x4;

__device__ inline unsigned short f2bf(float f) {
    union { float f; uint32_t u; } v; v.f = f;
    uint32_t u = v.u;
    u += 0x7fff + ((u >> 16) & 1);   // RNE
    return (unsigned short)(u >> 16);
}
__device__ inline uint32_t packbf2(float a, float b) {
    union { __hip_bfloat16 h; unsigned short u; } ca, cb;
    ca.h = __float2bfloat16(a);
    cb.h = __float2bfloat16(b);
    return (uint32_t)ca.u | ((uint32_t)cb.u << 16);
}
__device__ inline void bfsplit(float x, short* hi, short* lo) {
    union { __hip_bfloat16 h; unsigned short u; } c, d;
    c.h = __float2bfloat16(x);
    d.h = __float2bfloat16(x - __bfloat162float(c.h));
    *hi = (short)c.u; *lo = (short)d.u;
}

#if __has_builtin(__builtin_amdgcn_exp2f)
#define EXP2(x) __builtin_amdgcn_exp2f(x)
#else
#define EXP2(x) exp2f(x)
#endif

// ================= Fragment-major layouts (attn loads are base + lane*16B) ====
// Kf[b][tile16][m][lane][8] : elem K[tile*16+lo][m*32+hi*8+e],   lane = hi*16+lo
// Qf[b][tile16][kt][lane][8]: elem Q[tile*16+lo][kt*32+hi*8+e]   (pre-scaled log2e)
// Vf[b][tile32][vt][lane][8]: elem V[chan=vt*16+lo][tile*32+hi*8+e]
// WS: 6 MiB (QKV only — ctx round-trip eliminated by attn+oproj fusion).

// -------- QKV projection, 8-wave blocks: wave = (chan-group cg, token-tile tt) ------
// z=0: Q from xh (C=256). z=1: K AND V fused from xl (C=512), xl staged once.
// 1024 blocks x 8 waves = 4 blocks/CU = 8 waves/SIMD (vs 4 before); per-wave
// MFMA/LDS-read work halved; weight rows duplicated across tt-pair waves (L1 hits).
// VGPR cap 64 via launch_bounds(512,8) — old 4-wave version measured 56 with MORE
// per-wave state, so no spill expected (revert if FETCH/WRITE balloon).
#define CSTEP 64
__global__ __launch_bounds__(512, 8) void proj_mfma(
    const float* __restrict__ xl, const float* __restrict__ xh,
    const float* __restrict__ Wq, const float* __restrict__ bq,
    const float* __restrict__ Wk, const float* __restrict__ bk,
    const float* __restrict__ Wv, const float* __restrict__ bv,
    unsigned short* __restrict__ Qt, unsigned short* __restrict__ Kt,
    unsigned short* __restrict__ Vt)
{
    const int proj = blockIdx.z;
    const int b    = blockIdx.y;
    const int bidx = blockIdx.x;
    const int n0   = bidx * 32;
    const int tid  = threadIdx.x;
    const int wv   = tid >> 6;          // wave id 0..7
    const int cg   = wv & 3;            // chan group: out-chans [cg*16, +16)
    const int tt   = wv >> 2;           // token tile: tokens [n0+tt*16, +16)
    const int lane = tid & 63;
    const int lo   = lane & 15;
    const int hi   = lane >> 4;         // 0..3
    const int hi8  = hi * 8;

    __shared__ unsigned short XtHi[32][72];
    __shared__ unsigned short XtLo[32][72];

    const int tg = tid & 7;         // staging token-group 0..7
    const int t4 = tg * 4;          // token offset 0..28
    const int cR = tid >> 3;        // staging chan 0..63

    const float* X; int C;
    if (proj == 0) { X = xh; C = CHIGH; } else { X = xl; C = CLOW; }

    float4 pf0;                     // prefetch reg (4 tokens)

    #define LOADX(C0)                                                            \
        {                                                                        \
            pf0 = *(const float4*)(X + ((size_t)b*C + (C0) + cR)*N + n0 + t4);   \
        }

    #define STAGE()                                                              \
        {                                                                        \
            const int colx = cR ^ ((tg >> 1) << 3);                              \
            float vv[4] = {pf0.x, pf0.y, pf0.z, pf0.w};                          \
            _Pragma("unroll")                                                    \
            for (int i = 0; i < 4; ++i) {                                        \
                short h_, l_;                                                    \
                bfsplit(vv[i], &h_, &l_);                                        \
                XtHi[t4 + i][colx] = (unsigned short)h_;                         \
                XtLo[t4 + i][colx] = (unsigned short)l_;                         \
            }                                                                    \
        }

    #define WSPLITLD(WP, AH, AL)                                                 \
        {                                                                        \
            float4 w0 = *(const float4*)(WP);                                    \
            float4 w1 = *(const float4*)((WP) + 4);                              \
            float ww[8] = {w0.x,w0.y,w0.z,w0.w,w1.x,w1.y,w1.z,w1.w};             \
            _Pragma("unroll")                                                    \
            for (int i = 0; i < 8; ++i) {                                        \
                short h_, l_;                                                    \
                bfsplit(ww[i], &h_, &l_);                                        \
                AH[i] = h_; AL[i] = l_;                                          \
            }                                                                    \
        }

    // fragment-store offset (layout comment above; derived with cg like old wv)
    const size_t kqFragOff = (size_t)((((cg*2 + (hi>>1)) & 3)*16 + lo)*8 + (hi&1)*4);

    if (proj == 0) {
        // ---------- Q: wave computes chans [cg*16,+16) x tokens [tt*16,+16) --------
        f32x4 acc;
        #pragma unroll
        for (int r = 0; r < 4; ++r) acc[r] = bq[cg*16 + hi*4 + r];

        LOADX(0)
        for (int c0 = 0; c0 < CHIGH; c0 += CSTEP) {
            STAGE()
            __syncthreads();
            if (c0 + CSTEP < CHIGH) LOADX(c0 + CSTEP)

            #pragma unroll
            for (int m = 0; m < 2; ++m) {
                bf16x8 ah, al;
                const float* wp = Wq + (size_t)(cg*16 + lo)*CHIGH + c0 + m*32 + hi8;
                WSPLITLD(wp, ah, al)
                const int cx = (m*32 + hi8) ^ ((2*tt + (lo >> 3)) << 3);
                bf16x8 xhv = *(const bf16x8*)&XtHi[tt*16 + lo][cx];
                bf16x8 xlv = *(const bf16x8*)&XtLo[tt*16 + lo][cx];
                acc = __builtin_amdgcn_mfma_f32_16x16x32_bf16(ah, xhv, acc, 0, 0, 0);
                acc = __builtin_amdgcn_mfma_f32_16x16x32_bf16(ah, xlv, acc, 0, 0, 0);
                acc = __builtin_amdgcn_mfma_f32_16x16x32_bf16(al, xhv, acc, 0, 0, 0);
            }
            __syncthreads();
        }
        const float qs = 1.4426950408889634f;   // log2(e): attn uses raw exp2
        bf16x4 o;
        #pragma unroll
        for (int r = 0; r < 4; ++r) o[r] = (short)f2bf(acc[r] * qs);
        size_t base = (((size_t)b*256 + 2*bidx + tt)*2 + (cg>>1))*512;
        *(bf16x4*)&Qt[base + kqFragOff] = o;
    } else {
        // ---------- K + V fused (stage xl once) ----------
        f32x4 accK, accV;
        #pragma unroll
        for (int r = 0; r < 4; ++r) {
            accK[r] = bk[cg*16 + hi*4 + r];
            accV[r] = bv[cg*16 + hi*4 + r];
        }

        LOADX(0)
        for (int c0 = 0; c0 < CLOW; c0 += CSTEP) {
            STAGE()
            __syncthreads();
            if (c0 + CSTEP < CLOW) LOADX(c0 + CSTEP)

            #pragma unroll
            for (int m = 0; m < 2; ++m) {
                bf16x8 ahk, alk, ahv, alv;
                const float* wpk = Wk + (size_t)(cg*16 + lo)*CLOW + c0 + m*32 + hi8;
                const float* wpv = Wv + (size_t)(cg*16 + lo)*CLOW + c0 + m*32 + hi8;
                WSPLITLD(wpk, ahk, alk)
                WSPLITLD(wpv, ahv, alv)
                const int cx = (m*32 + hi8) ^ ((2*tt + (lo >> 3)) << 3);
                bf16x8 xhv = *(const bf16x8*)&XtHi[tt*16 + lo][cx];
                bf16x8 xlv = *(const bf16x8*)&XtLo[tt*16 + lo][cx];
                accK = __builtin_amdgcn_mfma_f32_16x16x32_bf16(ahk, xhv, accK, 0, 0, 0);
                accK = __builtin_amdgcn_mfma_f32_16x16x32_bf16(ahk, xlv, accK, 0, 0, 0);
                accK = __builtin_amdgcn_mfma_f32_16x16x32_bf16(alk, xhv, accK, 0, 0, 0);
                accV = __builtin_amdgcn_mfma_f32_16x16x32_bf16(ahv, xhv, accV, 0, 0, 0);
                accV = __builtin_amdgcn_mfma_f32_16x16x32_bf16(ahv, xlv, accV, 0, 0, 0);
                accV = __builtin_amdgcn_mfma_f32_16x16x32_bf16(alv, xhv, accV, 0, 0, 0);
            }
            __syncthreads();
        }

        // K fragment-major store
        bf16x4 o;
        #pragma unroll
        for (int r = 0; r < 4; ++r) o[r] = (short)f2bf(accK[r]);
        size_t kbase = (((size_t)b*256 + 2*bidx + tt)*2 + (cg>>1))*512;
        *(bf16x4*)&Kt[kbase + kqFragOff] = o;

        // V fragment-major store: chan = cg*16+hi*4+r, kv = n0+tt*16+lo
        const int hi_f = tt*2 + (lo >> 3);
        size_t vbase = ((size_t)b*128 + bidx)*2048 + (size_t)cg*512
                     + (size_t)hi_f*128 + (size_t)(lo & 7);
        #pragma unroll
        for (int r = 0; r < 4; ++r)
            Vt[vbase + (size_t)(hi*4 + r)*8] = f2bf(accV[r]);
    }
    #undef LOADX
    #undef STAGE
    #undef WSPLITLD
}

// ------- Fused flash attention + output projection + residual (R20, proven) -------
// Grid 512 (2/CU). xcd = bid&7; batch = xcd>>1; q-tile = (bid>>3)*2+(xcd&1) (32 rows).
// QT=2 attn, 8 waves kv-split, fragment-major loads, un-maxed softmax, LDS combine;
// normalized ctx kept in LDS; fused oproj: wave wv -> out chans [wv*32,+32).
// NOTE: 512 threads hard ceiling (R9/R14 spills at 1024).
#define WSPLIT 8
#define QT 2
__global__ __launch_bounds__(512, 4) void attn_oproj(
    const unsigned short* __restrict__ Qt,
    const unsigned short* __restrict__ Kt,
    const unsigned short* __restrict__ Vt,
    const float* __restrict__ Wo, const float* __restrict__ bo,
    const float* __restrict__ xh, float* __restrict__ out)
{
    const int bid = blockIdx.x;
    const int xcd = bid & 7;
    const int b   = xcd >> 1;                          // batch <- XCD pair
    const int q0  = ((bid >> 3) * 2 + (xcd & 1)) * 32; // q-tile base (32 rows)

    const int tid  = threadIdx.x;
    const int wv   = tid >> 6;    // 0..7
    const int lane = tid & 63;
    const int lo   = lane & 15;
    const int hi   = lane >> 4;   // 0..3
    const int hi8  = hi * 8;

    __shared__ float Olds[WSPLIT][32][68];   // 69.6 KB -> 2 blocks/CU
    __shared__ float llds[WSPLIT][32];

    const unsigned short* Kb = Kt + (size_t)b*N*KC;
    const unsigned short* Vb = Vt + (size_t)b*VC*N;
    const unsigned short* Qb = Qt + (size_t)b*N*KC;

    // Q fragments (fragment-major: one dwordx4 per lane)
    bf16x8 qf[2][QT];
    #pragma unroll
    for (int qt = 0; qt < QT; ++qt) {
        #pragma unroll
        for (int kt = 0; kt < 2; ++kt)
            qf[kt][qt] = *(const bf16x8*)&Qb[(((size_t)(q0>>4) + qt)*2 + kt)*512 + lane*8];
    }

    f32x4 O[4][QT] = {};           // [v-subtile][q-subtile]
    float l_run[QT] = {};

    const int kv0   = wv * (N/WSPLIT);
    const int kvend = kv0 + (N/WSPLIT);

    for (int kv = kv0; kv < kvend; kv += 32) {
        // ---- K A-frags + V B-frags, all coalesced lane*16B loads ----
        bf16x8 ka[2][2], va[4];
        #pragma unroll
        for (int j = 0; j < 2; ++j)
            #pragma unroll
            for (int m = 0; m < 2; ++m)
                ka[j][m] = *(const bf16x8*)&Kb[(((size_t)(kv>>4) + j)*2 + m)*512 + lane*8];
        #pragma unroll
        for (int vt = 0; vt < 4; ++vt)
            va[vt] = *(const bf16x8*)&Vb[((size_t)(kv>>5))*2048 + vt*512 + lane*8];

        #pragma unroll
        for (int qt = 0; qt < QT; ++qt) {
            // ---- S^T = K · Q^T : lane(hi,lo) reg r = P^T[4hi+r][q=lo] ----
            f32x4 st[2];
            #pragma unroll
            for (int j = 0; j < 2; ++j) {
                f32x4 z = {};
                z     = __builtin_amdgcn_mfma_f32_16x16x32_bf16(ka[j][0], qf[0][qt], z, 0, 0, 0);
                st[j] = __builtin_amdgcn_mfma_f32_16x16x32_bf16(ka[j][1], qf[1][qt], z, 0, 0, 0);
            }
            // ---- p = 2^s (Q pre-scaled by log2e); in-lane bf16 pack ----
            uint32_t pk[2][2];
            #pragma unroll
            for (int j = 0; j < 2; ++j) {
                float p0 = EXP2(st[j][0]);
                float p1 = EXP2(st[j][1]);
                float p2 = EXP2(st[j][2]);
                float p3 = EXP2(st[j][3]);
                l_run[qt] += (p0 + p1) + (p2 + p3);
                pk[j][0] = packbf2(p0, p1);
                pk[j][1] = packbf2(p2, p3);
            }
            // ---- P^T(D-layout) -> P(A-frag) via 8 shfl + selects ----
            union { int w[4]; bf16x8 v; } pa;
            #pragma unroll
            for (int w = 0; w < 4; ++w) {
                int src = (2*(hi & 1) + (w >> 1))*16 + lo;
                int t0 = __shfl((int)pk[0][w & 1], src);
                int t1 = __shfl((int)pk[1][w & 1], src);
                pa.w[w] = (hi < 2) ? t0 : t1;
            }
            // ---- PV ----
            #pragma unroll
            for (int vt = 0; vt < 4; ++vt)
                O[vt][qt] = __builtin_amdgcn_mfma_f32_16x16x32_bf16(pa.v, va[vt], O[vt][qt], 0, 0, 0);
        }
    }

    // ---- reduce l across the 4 hi-groups; every lane gets l[q=lo] ----
    #pragma unroll
    for (int qt = 0; qt < QT; ++qt) {
        float s = l_run[qt];
        s += __shfl_xor(s, 16);
        s += __shfl_xor(s, 32);
        l_run[qt] = s;
    }

    // ---- write per-wave partials ----
    #pragma unroll
    for (int qt = 0; qt < QT; ++qt) {
        #pragma unroll
        for (int vt = 0; vt < 4; ++vt)
            #pragma unroll
            for (int r = 0; r < 4; ++r)
                Olds[wv][qt*16 + hi*4 + r][vt*16 + lo] = O[vt][qt][r];
        if (lane < 16) llds[wv][qt*16 + lo] = l_run[qt];
    }
    __syncthreads();

    // ---- combine kv-split partials, normalize; keep ctx in LDS (Olds[0]) ----
    {
        const int row = tid >> 4;          // 0..31
        const int c4  = (tid & 15) * 4;    // 0..60
        float L = 0.f;
        #pragma unroll
        for (int w = 0; w < WSPLIT; ++w) L += llds[w][row];
        float4 o = {0.f, 0.f, 0.f, 0.f};
        #pragma unroll
        for (int w = 0; w < WSPLIT; ++w) {
            float4 ow = *(const float4*)&Olds[w][row][c4];
            o.x += ow.x; o.y += ow.y; o.z += ow.z; o.w += ow.w;
        }
        float rL = 1.0f / L;
        o.x *= rL; o.y *= rL; o.z *= rL; o.w *= rL;
        *(float4*)&Olds[0][row][c4] = o;
    }
    __syncthreads();

    // ================== fused output projection + residual ======================
    {
        bf16x8 bh[2][2], bl[2][2];
        #pragma unroll
        for (int tt = 0; tt < 2; ++tt) {
            #pragma unroll
            for (int j = 0; j < 2; ++j) {
                const float* cp = &Olds[0][tt*16 + lo][j*32 + hi8];
                float4 c0 = *(const float4*)(cp);
                float4 c1 = *(const float4*)(cp + 4);
                float cc[8] = {c0.x,c0.y,c0.z,c0.w,c1.x,c1.y,c1.z,c1.w};
                #pragma unroll
                for (int i = 0; i < 8; ++i) {
                    short h_, l_;
                    bfsplit(cc[i], &h_, &l_);
                    bh[tt][j][i] = h_;
                    bl[tt][j][i] = l_;
                }
            }
        }
        #pragma unroll
        for (int ct = 0; ct < 2; ++ct) {
            const int chan0 = wv*32 + ct*16;
            bf16x8 ah[2], al[2];
            #pragma unroll
            for (int j = 0; j < 2; ++j) {
                const float* wp = Wo + (size_t)(chan0 + lo)*VC + j*32 + hi8;
                float4 w0 = *(const float4*)(wp);
                float4 w1 = *(const float4*)(wp + 4);
                float ww[8] = {w0.x,w0.y,w0.z,w0.w,w1.x,w1.y,w1.z,w1.w};
                #pragma unroll
                for (int i = 0; i < 8; ++i) {
                    short h_, l_;
                    bfsplit(ww[i], &h_, &l_);
                    ah[j][i] = h_;
                    al[j][i] = l_;
                }
            }
            #pragma unroll
            for (int tt = 0; tt < 2; ++tt) {
                f32x4 acc;
                #pragma unroll
                for (int r = 0; r < 4; ++r) acc[r] = bo[chan0 + hi*4 + r];
                #pragma unroll
                for (int j = 0; j < 2; ++j) {
                    acc = __builtin_amdgcn_mfma_f32_16x16x32_bf16(ah[j], bh[tt][j], acc, 0, 0, 0);
                    acc = __builtin_amdgcn_mfma_f32_16x16x32_bf16(ah[j], bl[tt][j], acc, 0, 0, 0);
                    acc = __builtin_amdgcn_mfma_f32_16x16x32_bf16(al[j], bh[tt][j], acc, 0, 0, 0);
                }
                #pragma unroll
                for (int r = 0; r < 4; ++r) {
                    size_t idx = ((size_t)b*CHIGH + chan0 + hi*4 + r)*N + q0 + tt*16 + lo;
                    out[idx] = acc[r] + xh[idx];
                }
            }
        }
    }
}

extern "C" void kernel_launch(void* const* d_in, const int* in_sizes, int n_in,
                              void* d_out, int out_size, void* d_ws, size_t ws_size,
                              hipStream_t stream) {
    const float* xl = (const float*)d_in[0];
    const float* xh = (const float*)d_in[1];
    const float* Wq = (const float*)d_in[2];
    const float* bq = (const float*)d_in[3];
    const float* Wk = (const float*)d_in[4];
    const float* bk = (const float*)d_in[5];
    const float* Wv = (const float*)d_in[6];
    const float* bv = (const float*)d_in[7];
    const float* Wo = (const float*)d_in[8];
    const float* bo = (const float*)d_in[9];
    float* out = (float*)d_out;

    unsigned short* Qt = (unsigned short*)d_ws;                 // [B][N*64] bf16 frag-major (x log2e)
    unsigned short* Kt = Qt + (size_t)B*N*KC;                   // [B][N*64] bf16 frag-major
    unsigned short* Vt = Kt + (size_t)B*N*KC;                   // [B][64*N] bf16 frag-major

    hipLaunchKernelGGL(proj_mfma, dim3(N/32, B, 2), dim3(512), 0, stream,
                       xl, xh, Wq, bq, Wk, bk, Wv, bv, Qt, Kt, Vt);
    hipLaunchKernelGGL(attn_oproj, dim3(512), dim3(512), 0, stream,
                       Qt, Kt, Vt, Wo, bo, xh, out);
}

// Round 22
// 62.703 us; speedup vs baseline: 1.2632x; 1.2632x over previous
//
#include <hip/hip_runtime.h>
#include <hip/hip_bf16.h>
#include <math.h>
#include <stdint.h>

#define B 4
#define CLOW 512
#define CHIGH 256
#define KC 64
#define VC 64
#define N 4096  // 64*64 tokens

typedef __attribute__((ext_vector_type(8))) short bf16x8;
typedef __attribute__((ext_vector_type(4))) short bf16x4;
typedef __attribute__((ext_vector_type(4))) float f32x4;

__device__ inline unsigned short f2bf(float f) {
    union { float f; uint32_t u; } v; v.f = f;
    uint32_t u = v.u;
    u += 0x7fff + ((u >> 16) & 1);   // RNE
    return (unsigned short)(u >> 16);
}
__device__ inline uint32_t packbf2(float a, float b) {
    union { __hip_bfloat16 h; unsigned short u; } ca, cb;
    ca.h = __float2bfloat16(a);
    cb.h = __float2bfloat16(b);
    return (uint32_t)ca.u | ((uint32_t)cb.u << 16);
}
__device__ inline void bfsplit(float x, short* hi, short* lo) {
    union { __hip_bfloat16 h; unsigned short u; } c, d;
    c.h = __float2bfloat16(x);
    d.h = __float2bfloat16(x - __bfloat162float(c.h));
    *hi = (short)c.u; *lo = (short)d.u;
}

#if __has_builtin(__builtin_amdgcn_exp2f)
#define EXP2(x) __builtin_amdgcn_exp2f(x)
#else
#define EXP2(x) exp2f(x)
#endif

// ================= Fragment-major layouts (attn loads are base + lane*16B) ====
// Kf[b][tile16][m][lane][8] : elem K[tile*16+lo][m*32+hi*8+e],   lane = hi*16+lo
// Qf[b][tile16][kt][lane][8]: elem Q[tile*16+lo][kt*32+hi*8+e]   (pre-scaled log2e)
// Vf[b][tile32][vt][lane][8]: elem V[chan=vt*16+lo][tile*32+hi*8+e]
// WS: 6 MiB (QKV only — ctx round-trip eliminated by attn+oproj fusion).

// ---------------- QKV projection, 4-wave blocks, 32-token tiles, CSTEP=128 ---------
// z=0: Q from xh (C=256). z=1: K AND V fused from xl (C=512), xl staged once.
// CSTEP=128 halves barrier count vs R20 (K+V: 8->4 chunks) — proj is
// barrier-serialization-bound (R15/R19/R21 falsified occupancy/weight-VALU theories).
// Swizzle: write col^=(tokengroup<<3), read key=2tt+(lo>>3) — identical mapping.
#define CSTEP 128
__global__ __launch_bounds__(256, 4) void proj_mfma(
    const float* __restrict__ xl, const float* __restrict__ xh,
    const float* __restrict__ Wq, const float* __restrict__ bq,
    const float* __restrict__ Wk, const float* __restrict__ bk,
    const float* __restrict__ Wv, const float* __restrict__ bv,
    unsigned short* __restrict__ Qt, unsigned short* __restrict__ Kt,
    unsigned short* __restrict__ Vt)
{
    const int proj = blockIdx.z;
    const int b    = blockIdx.y;
    const int bidx = blockIdx.x;
    const int n0   = bidx * 32;
    const int tid  = threadIdx.x;
    const int wv   = tid >> 6;          // wave id 0..3
    const int lane = tid & 63;
    const int lo   = lane & 15;
    const int hi   = lane >> 4;         // 0..3
    const int hi8  = hi * 8;

    __shared__ unsigned short XtHi[32][136];   // 128 chans + pad (272B rows)
    __shared__ unsigned short XtLo[32][136];

    const int tS = tid & 3;         // staging token-group 0..3
    const int t8 = tS * 8;          // token offset 0..24
    const int cR = tid >> 2;        // staging chan 0..63 (+64 for slice 1)

    const float* X; int C;
    if (proj == 0) { X = xh; C = CHIGH; } else { X = xl; C = CLOW; }

    float4 pf[2][2];                // prefetch regs: [slice][tok-half]

    #define LOADX(C0)                                                            \
        {                                                                        \
            _Pragma("unroll")                                                    \
            for (int s = 0; s < 2; ++s) {                                        \
                const float* src = X + ((size_t)b*C + (C0) + cR + 64*s)*N + n0 + t8; \
                pf[s][0] = *(const float4*)src;                                  \
                pf[s][1] = *(const float4*)(src + 4);                            \
            }                                                                    \
        }

    #define STAGE()                                                              \
        {                                                                        \
            _Pragma("unroll")                                                    \
            for (int s = 0; s < 2; ++s) {                                        \
                const int colx = (cR + 64*s) ^ (tS << 3);                        \
                float vv[8] = {pf[s][0].x, pf[s][0].y, pf[s][0].z, pf[s][0].w,   \
                               pf[s][1].x, pf[s][1].y, pf[s][1].z, pf[s][1].w};  \
                _Pragma("unroll")                                                \
                for (int i = 0; i < 8; ++i) {                                    \
                    short h_, l_;                                                \
                    bfsplit(vv[i], &h_, &l_);                                    \
                    XtHi[t8 + i][colx] = (unsigned short)h_;                     \
                    XtLo[t8 + i][colx] = (unsigned short)l_;                     \
                }                                                                \
            }                                                                    \
        }

    #define WSPLITLD(WP, AH, AL)                                                 \
        {                                                                        \
            float4 w0 = *(const float4*)(WP);                                    \
            float4 w1 = *(const float4*)((WP) + 4);                              \
            float ww[8] = {w0.x,w0.y,w0.z,w0.w,w1.x,w1.y,w1.z,w1.w};             \
            _Pragma("unroll")                                                    \
            for (int i = 0; i < 8; ++i) {                                        \
                short h_, l_;                                                    \
                bfsplit(ww[i], &h_, &l_);                                        \
                AH[i] = h_; AL[i] = l_;                                          \
            }                                                                    \
        }

    // fragment-store offset (layout comment above)
    const size_t kqFragOff = (size_t)((((wv*2 + (hi>>1)) & 3)*16 + lo)*8 + (hi&1)*4);

    if (proj == 0) {
        // ---------- Q ----------
        f32x4 acc[2];
        #pragma unroll
        for (int t = 0; t < 2; ++t)
            #pragma unroll
            for (int r = 0; r < 4; ++r) acc[t][r] = bq[wv*16 + hi*4 + r];

        LOADX(0)
        for (int c0 = 0; c0 < CHIGH; c0 += CSTEP) {
            STAGE()
            __syncthreads();
            if (c0 + CSTEP < CHIGH) LOADX(c0 + CSTEP)

            #pragma unroll
            for (int m = 0; m < 4; ++m) {
                bf16x8 ah, al;
                const float* wp = Wq + (size_t)(wv*16 + lo)*CHIGH + c0 + m*32 + hi8;
                WSPLITLD(wp, ah, al)
                #pragma unroll
                for (int tt = 0; tt < 2; ++tt) {
                    const int cx = (m*32 + hi8) ^ ((2*tt + (lo >> 3)) << 3);
                    bf16x8 xhv = *(const bf16x8*)&XtHi[tt*16 + lo][cx];
                    bf16x8 xlv = *(const bf16x8*)&XtLo[tt*16 + lo][cx];
                    acc[tt] = __builtin_amdgcn_mfma_f32_16x16x32_bf16(ah, xhv, acc[tt], 0, 0, 0);
                    acc[tt] = __builtin_amdgcn_mfma_f32_16x16x32_bf16(ah, xlv, acc[tt], 0, 0, 0);
                    acc[tt] = __builtin_amdgcn_mfma_f32_16x16x32_bf16(al, xhv, acc[tt], 0, 0, 0);
                }
            }
            __syncthreads();
        }
        const float qs = 1.4426950408889634f;   // log2(e): attn uses raw exp2
        #pragma unroll
        for (int t = 0; t < 2; ++t) {
            bf16x4 o;
            #pragma unroll
            for (int r = 0; r < 4; ++r) o[r] = (short)f2bf(acc[t][r] * qs);
            size_t base = (((size_t)b*256 + 2*bidx + t)*2 + (wv>>1))*512;
            *(bf16x4*)&Qt[base + kqFragOff] = o;
        }
    } else {
        // ---------- K + V fused (stage xl once) ----------
        f32x4 accK[2], accV[2];
        #pragma unroll
        for (int t = 0; t < 2; ++t)
            #pragma unroll
            for (int r = 0; r < 4; ++r) {
                accK[t][r] = bk[wv*16 + hi*4 + r];
                accV[t][r] = bv[wv*16 + hi*4 + r];
            }

        LOADX(0)
        for (int c0 = 0; c0 < CLOW; c0 += CSTEP) {
            STAGE()
            __syncthreads();
            if (c0 + CSTEP < CLOW) LOADX(c0 + CSTEP)

            #pragma unroll
            for (int m = 0; m < 4; ++m) {
                bf16x8 ahk, alk, ahv, alv;
                const float* wpk = Wk + (size_t)(wv*16 + lo)*CLOW + c0 + m*32 + hi8;
                const float* wpv = Wv + (size_t)(wv*16 + lo)*CLOW + c0 + m*32 + hi8;
                WSPLITLD(wpk, ahk, alk)
                WSPLITLD(wpv, ahv, alv)
                #pragma unroll
                for (int tt = 0; tt < 2; ++tt) {
                    const int cx = (m*32 + hi8) ^ ((2*tt + (lo >> 3)) << 3);
                    bf16x8 xhv = *(const bf16x8*)&XtHi[tt*16 + lo][cx];
                    bf16x8 xlv = *(const bf16x8*)&XtLo[tt*16 + lo][cx];
                    accK[tt] = __builtin_amdgcn_mfma_f32_16x16x32_bf16(ahk, xhv, accK[tt], 0, 0, 0);
                    accK[tt] = __builtin_amdgcn_mfma_f32_16x16x32_bf16(ahk, xlv, accK[tt], 0, 0, 0);
                    accK[tt] = __builtin_amdgcn_mfma_f32_16x16x32_bf16(alk, xhv, accK[tt], 0, 0, 0);
                    accV[tt] = __builtin_amdgcn_mfma_f32_16x16x32_bf16(ahv, xhv, accV[tt], 0, 0, 0);
                    accV[tt] = __builtin_amdgcn_mfma_f32_16x16x32_bf16(ahv, xlv, accV[tt], 0, 0, 0);
                    accV[tt] = __builtin_amdgcn_mfma_f32_16x16x32_bf16(alv, xhv, accV[tt], 0, 0, 0);
                }
            }
            __syncthreads();
        }

        #pragma unroll
        for (int t = 0; t < 2; ++t) {
            // K fragment-major store
            bf16x4 o;
            #pragma unroll
            for (int r = 0; r < 4; ++r) o[r] = (short)f2bf(accK[t][r]);
            size_t kbase = (((size_t)b*256 + 2*bidx + t)*2 + (wv>>1))*512;
            *(bf16x4*)&Kt[kbase + kqFragOff] = o;

            // V fragment-major store: chan = wv*16+hi*4+r, kv = n0+t*16+lo
            const int hi_f = t*2 + (lo >> 3);
            size_t vbase = ((size_t)b*128 + bidx)*2048 + (size_t)wv*512
                         + (size_t)hi_f*128 + (size_t)(lo & 7);
            #pragma unroll
            for (int r = 0; r < 4; ++r)
                Vt[vbase + (size_t)(hi*4 + r)*8] = f2bf(accV[t][r]);
        }
    }
    #undef LOADX
    #undef STAGE
    #undef WSPLITLD
}

// ------- Fused flash attention + output projection + residual (R20, proven) -------
// Grid 512 (2/CU). xcd = bid&7; batch = xcd>>1; q-tile = (bid>>3)*2+(xcd&1) (32 rows).
// QT=2 attn, 8 waves kv-split, fragment-major loads, un-maxed softmax, LDS combine;
// normalized ctx kept in LDS; fused oproj: wave wv -> out chans [wv*32,+32).
// NOTE: 512 threads hard ceiling (R9/R14 spills at 1024).
#define WSPLIT 8
#define QT 2
__global__ __launch_bounds__(512, 4) void attn_oproj(
    const unsigned short* __restrict__ Qt,
    const unsigned short* __restrict__ Kt,
    const unsigned short* __restrict__ Vt,
    const float* __restrict__ Wo, const float* __restrict__ bo,
    const float* __restrict__ xh, float* __restrict__ out)
{
    const int bid = blockIdx.x;
    const int xcd = bid & 7;
    const int b   = xcd >> 1;                          // batch <- XCD pair
    const int q0  = ((bid >> 3) * 2 + (xcd & 1)) * 32; // q-tile base (32 rows)

    const int tid  = threadIdx.x;
    const int wv   = tid >> 6;    // 0..7
    const int lane = tid & 63;
    const int lo   = lane & 15;
    const int hi   = lane >> 4;   // 0..3
    const int hi8  = hi * 8;

    __shared__ float Olds[WSPLIT][32][68];   // 69.6 KB -> 2 blocks/CU
    __shared__ float llds[WSPLIT][32];

    const unsigned short* Kb = Kt + (size_t)b*N*KC;
    const unsigned short* Vb = Vt + (size_t)b*VC*N;
    const unsigned short* Qb = Qt + (size_t)b*N*KC;

    // Q fragments (fragment-major: one dwordx4 per lane)
    bf16x8 qf[2][QT];
    #pragma unroll
    for (int qt = 0; qt < QT; ++qt) {
        #pragma unroll
        for (int kt = 0; kt < 2; ++kt)
            qf[kt][qt] = *(const bf16x8*)&Qb[(((size_t)(q0>>4) + qt)*2 + kt)*512 + lane*8];
    }

    f32x4 O[4][QT] = {};           // [v-subtile][q-subtile]
    float l_run[QT] = {};

    const int kv0   = wv * (N/WSPLIT);
    const int kvend = kv0 + (N/WSPLIT);

    for (int kv = kv0; kv < kvend; kv += 32) {
        // ---- K A-frags + V B-frags, all coalesced lane*16B loads ----
        bf16x8 ka[2][2], va[4];
        #pragma unroll
        for (int j = 0; j < 2; ++j)
            #pragma unroll
            for (int m = 0; m < 2; ++m)
                ka[j][m] = *(const bf16x8*)&Kb[(((size_t)(kv>>4) + j)*2 + m)*512 + lane*8];
        #pragma unroll
        for (int vt = 0; vt < 4; ++vt)
            va[vt] = *(const bf16x8*)&Vb[((size_t)(kv>>5))*2048 + vt*512 + lane*8];

        #pragma unroll
        for (int qt = 0; qt < QT; ++qt) {
            // ---- S^T = K · Q^T : lane(hi,lo) reg r = P^T[4hi+r][q=lo] ----
            f32x4 st[2];
            #pragma unroll
            for (int j = 0; j < 2; ++j) {
                f32x4 z = {};
                z     = __builtin_amdgcn_mfma_f32_16x16x32_bf16(ka[j][0], qf[0][qt], z, 0, 0, 0);
                st[j] = __builtin_amdgcn_mfma_f32_16x16x32_bf16(ka[j][1], qf[1][qt], z, 0, 0, 0);
            }
            // ---- p = 2^s (Q pre-scaled by log2e); in-lane bf16 pack ----
            uint32_t pk[2][2];
            #pragma unroll
            for (int j = 0; j < 2; ++j) {
                float p0 = EXP2(st[j][0]);
                float p1 = EXP2(st[j][1]);
                float p2 = EXP2(st[j][2]);
                float p3 = EXP2(st[j][3]);
                l_run[qt] += (p0 + p1) + (p2 + p3);
                pk[j][0] = packbf2(p0, p1);
                pk[j][1] = packbf2(p2, p3);
            }
            // ---- P^T(D-layout) -> P(A-frag) via 8 shfl + selects ----
            union { int w[4]; bf16x8 v; } pa;
            #pragma unroll
            for (int w = 0; w < 4; ++w) {
                int src = (2*(hi & 1) + (w >> 1))*16 + lo;
                int t0 = __shfl((int)pk[0][w & 1], src);
                int t1 = __shfl((int)pk[1][w & 1], src);
                pa.w[w] = (hi < 2) ? t0 : t1;
            }
            // ---- PV ----
            #pragma unroll
            for (int vt = 0; vt < 4; ++vt)
                O[vt][qt] = __builtin_amdgcn_mfma_f32_16x16x32_bf16(pa.v, va[vt], O[vt][qt], 0, 0, 0);
        }
    }

    // ---- reduce l across the 4 hi-groups; every lane gets l[q=lo] ----
    #pragma unroll
    for (int qt = 0; qt < QT; ++qt) {
        float s = l_run[qt];
        s += __shfl_xor(s, 16);
        s += __shfl_xor(s, 32);
        l_run[qt] = s;
    }

    // ---- write per-wave partials ----
    #pragma unroll
    for (int qt = 0; qt < QT; ++qt) {
        #pragma unroll
        for (int vt = 0; vt < 4; ++vt)
            #pragma unroll
            for (int r = 0; r < 4; ++r)
                Olds[wv][qt*16 + hi*4 + r][vt*16 + lo] = O[vt][qt][r];
        if (lane < 16) llds[wv][qt*16 + lo] = l_run[qt];
    }
    __syncthreads();

    // ---- combine kv-split partials, normalize; keep ctx in LDS (Olds[0]) ----
    {
        const int row = tid >> 4;          // 0..31
        const int c4  = (tid & 15) * 4;    // 0..60
        float L = 0.f;
        #pragma unroll
        for (int w = 0; w < WSPLIT; ++w) L += llds[w][row];
        float4 o = {0.f, 0.f, 0.f, 0.f};
        #pragma unroll
        for (int w = 0; w < WSPLIT; ++w) {
            float4 ow = *(const float4*)&Olds[w][row][c4];
            o.x += ow.x; o.y += ow.y; o.z += ow.z; o.w += ow.w;
        }
        float rL = 1.0f / L;
        o.x *= rL; o.y *= rL; o.z *= rL; o.w *= rL;
        *(float4*)&Olds[0][row][c4] = o;
    }
    __syncthreads();

    // ================== fused output projection + residual ======================
    {
        bf16x8 bh[2][2], bl[2][2];
        #pragma unroll
        for (int tt = 0; tt < 2; ++tt) {
            #pragma unroll
            for (int j = 0; j < 2; ++j) {
                const float* cp = &Olds[0][tt*16 + lo][j*32 + hi8];
                float4 c0 = *(const float4*)(cp);
                float4 c1 = *(const float4*)(cp + 4);
                float cc[8] = {c0.x,c0.y,c0.z,c0.w,c1.x,c1.y,c1.z,c1.w};
                #pragma unroll
                for (int i = 0; i < 8; ++i) {
                    short h_, l_;
                    bfsplit(cc[i], &h_, &l_);
                    bh[tt][j][i] = h_;
                    bl[tt][j][i] = l_;
                }
            }
        }
        #pragma unroll
        for (int ct = 0; ct < 2; ++ct) {
            const int chan0 = wv*32 + ct*16;
            bf16x8 ah[2], al[2];
            #pragma unroll
            for (int j = 0; j < 2; ++j) {
                const float* wp = Wo + (size_t)(chan0 + lo)*VC + j*32 + hi8;
                float4 w0 = *(const float4*)(wp);
                float4 w1 = *(const float4*)(wp + 4);
                float ww[8] = {w0.x,w0.y,w0.z,w0.w,w1.x,w1.y,w1.z,w1.w};
                #pragma unroll
                for (int i = 0; i < 8; ++i) {
                    short h_, l_;
                    bfsplit(ww[i], &h_, &l_);
                    ah[j][i] = h_;
                    al[j][i] = l_;
                }
            }
            #pragma unroll
            for (int tt = 0; tt < 2; ++tt) {
                f32x4 acc;
                #pragma unroll
                for (int r = 0; r < 4; ++r) acc[r] = bo[chan0 + hi*4 + r];
                #pragma unroll
                for (int j = 0; j < 2; ++j) {
                    acc = __builtin_amdgcn_mfma_f32_16x16x32_bf16(ah[j], bh[tt][j], acc, 0, 0, 0);
                    acc = __builtin_amdgcn_mfma_f32_16x16x32_bf16(ah[j], bl[tt][j], acc, 0, 0, 0);
                    acc = __builtin_amdgcn_mfma_f32_16x16x32_bf16(al[j], bh[tt][j], acc, 0, 0, 0);
                }
                #pragma unroll
                for (int r = 0; r < 4; ++r) {
                    size_t idx = ((size_t)b*CHIGH + chan0 + hi*4 + r)*N + q0 + tt*16 + lo;
                    out[idx] = acc[r] + xh[idx];
                }
            }
        }
    }
}

extern "C" void kernel_launch(void* const* d_in, const int* in_sizes, int n_in,
                              void* d_out, int out_size, void* d_ws, size_t ws_size,
                              hipStream_t stream) {
    const float* xl = (const float*)d_in[0];
    const float* xh = (const float*)d_in[1];
    const float* Wq = (const float*)d_in[2];
    const float* bq = (const float*)d_in[3];
    const float* Wk = (const float*)d_in[4];
    const float* bk = (const float*)d_in[5];
    const float* Wv = (const float*)d_in[6];
    const float* bv = (const float*)d_in[7];
    const float* Wo = (const float*)d_in[8];
    const float* bo = (const float*)d_in[9];
    float* out = (float*)d_out;

    unsigned short* Qt = (unsigned short*)d_ws;                 // [B][N*64] bf16 frag-major (x log2e)
    unsigned short* Kt = Qt + (size_t)B*N*KC;                   // [B][N*64] bf16 frag-major
    unsigned short* Vt = Kt + (size_t)B*N*KC;                   // [B][64*N] bf16 frag-major

    hipLaunchKernelGGL(proj_mfma, dim3(N/32, B, 2), dim3(256), 0, stream,
                       xl, xh, Wq, bq, Wk, bk, Wv, bv, Qt, Kt, Vt);
    hipLaunchKernelGGL(attn_oproj, dim3(512), dim3(512), 0, stream,
                       Qt, Kt, Vt, Wo, bo, xh, out);
}